// Round 9
// baseline (227.824 us; speedup 1.0000x reference)
//
#include <hip/hip_runtime.h>

// DCNv3 forward, FP32 I/O. N=8, H=W=64, C=256, G=16, GC=16, K=3, P=9. L=32768.
//
// Round-9:
//  - k_gemm templated on TWOP: in-proj & head GEMMs use 1 MFMA product
//    (plain bf16 W), out-proj keeps hi+lo 2-product (writes final output).
//  - k_gather v2: 1 thread per (pixel,group), 16 ch/thread; head staged to
//    LDS bf16 via uint4; softmax thread-private (single barrier).
// Dispatches: k_prep, k_dwln, gemm(in,1p), gemm(head,1p), k_gather, gemm(out,2p).
// Fallback: round-3 minimal path (33.5 MB) if ws too small.

#define LL 32768
#define CC 256

typedef __bf16 bf16;
typedef __bf16 bf16x4 __attribute__((ext_vector_type(4)));
typedef __bf16 bf16x8 __attribute__((ext_vector_type(8)));
typedef float f32x4v __attribute__((ext_vector_type(4)));

__device__ __forceinline__ void gload16(const bf16* g, const bf16* lds_base) {
    __builtin_amdgcn_global_load_lds(
        (const __attribute__((address_space(1))) void*)g,
        (__attribute__((address_space(3))) void*)lds_base, 16, 0, 0);
}

// ---------------- weight prep: cvt + pack + pad, one launch ---------------
__global__ __launch_bounds__(256) void k_prep(
    const float* __restrict__ in_w, const float* __restrict__ off_w,
    const float* __restrict__ mask_w, const float* __restrict__ out_w,
    const float* __restrict__ dw_w, const float* __restrict__ off_b,
    const float* __restrict__ mask_b,
    bf16* __restrict__ in_h, bf16* __restrict__ in_l,
    bf16* __restrict__ hw_h, bf16* __restrict__ hw_l,
    bf16* __restrict__ out_h, bf16* __restrict__ out_l,
    float* __restrict__ dwT, float* __restrict__ hbias) {
    int idx = blockIdx.x * 256 + threadIdx.x;
    if (idx < 60416) {
        const float* s; bf16 *hi, *lo; int i;
        if (idx < 16384)      { s = in_w;   hi = in_h;          lo = in_l;          i = idx; }
        else if (idx < 34816) { s = off_w;  hi = hw_h;          lo = hw_l;          i = idx - 16384; }
        else if (idx < 44032) { s = mask_w; hi = hw_h + 73728;  lo = hw_l + 73728;  i = idx - 34816; }
        else                  { s = out_w;  hi = out_h;         lo = out_l;         i = idx - 44032; }
        float4 v = *(const float4*)(s + (size_t)i * 4);
        bf16x4 h, l;
        h[0] = (bf16)v.x; l[0] = (bf16)(v.x - (float)h[0]);
        h[1] = (bf16)v.y; l[1] = (bf16)(v.y - (float)h[1]);
        h[2] = (bf16)v.z; l[2] = (bf16)(v.z - (float)h[2]);
        h[3] = (bf16)v.w; l[3] = (bf16)(v.w - (float)h[3]);
        *(bf16x4*)(hi + (size_t)i * 4) = h;
        *(bf16x4*)(lo + (size_t)i * 4) = l;
    } else if (idx < 62720) {
        int e = idx - 60416;
        int c = e & 255, j = e >> 8;
        dwT[j * 256 + c] = dw_w[c * 9 + j];
    } else if (idx < 63232) {
        int e = idx - 62720;   // 0..511
        hbias[e] = (e < 288) ? off_b[e] : (e < 432 ? mask_b[e - 288] : 0.f);
    } else if (idx < 68352) {
        int e = idx - 63232;   // 0..5119 : zero-fill hw rows 432..511
        bf16x4 z = {(bf16)0.f, (bf16)0.f, (bf16)0.f, (bf16)0.f};
        *(bf16x4*)(hw_h + 110592 + (size_t)e * 4) = z;
        *(bf16x4*)(hw_l + 110592 + (size_t)e * 4) = z;
    }
}

// ------- dwconv3x3 + LN + GELU (wave/pixel); also emits xb = bf16(x) ------
__global__ __launch_bounds__(256) void k_dwln(
    const float* __restrict__ x, const float* __restrict__ dwT,
    const float* __restrict__ dw_b, const float* __restrict__ ln_g,
    const float* __restrict__ ln_b, bf16* __restrict__ x1h,
    bf16* __restrict__ xb) {
    int t = threadIdx.x;
    int q = t >> 6, u = t & 63;
    int l = blockIdx.x * 4 + q;
    int w = l & 63, h = (l >> 6) & 63, n = l >> 12;
    int c0 = u * 4;

    float4 acc = *(const float4*)(dw_b + c0);
    float4 xc = {0.f, 0.f, 0.f, 0.f};
#pragma unroll
    for (int kh = 0; kh < 3; ++kh) {
        int hh = h + kh - 1;
        if (hh < 0 || hh >= 64) continue;
#pragma unroll
        for (int kw = 0; kw < 3; ++kw) {
            int ww = w + kw - 1;
            if (ww < 0 || ww >= 64) continue;
            float4 xv = *(const float4*)(x + (size_t)(((n * 64 + hh) * 64) + ww) * CC + c0);
            if (kh == 1 && kw == 1) xc = xv;
            float4 wv = *(const float4*)(dwT + (kh * 3 + kw) * 256 + c0);
            acc.x += xv.x * wv.x; acc.y += xv.y * wv.y;
            acc.z += xv.z * wv.z; acc.w += xv.w * wv.w;
        }
    }
    bf16x4 xcb;
    xcb[0] = (bf16)xc.x; xcb[1] = (bf16)xc.y;
    xcb[2] = (bf16)xc.z; xcb[3] = (bf16)xc.w;
    *(bf16x4*)(xb + (size_t)l * CC + c0) = xcb;

    float s = acc.x + acc.y + acc.z + acc.w;
    float ss = acc.x * acc.x + acc.y * acc.y + acc.z * acc.z + acc.w * acc.w;
#pragma unroll
    for (int d = 1; d < 64; d <<= 1) {
        s += __shfl_xor(s, d);
        ss += __shfl_xor(ss, d);
    }
    float mean = s * (1.0f / 256.0f);
    float var = ss * (1.0f / 256.0f) - mean * mean;
    float rstd = rsqrtf(var + 1e-6f);
    float4 gv = *(const float4*)(ln_g + c0);
    float4 bv = *(const float4*)(ln_b + c0);
    float xn0 = (acc.x - mean) * rstd * gv.x + bv.x;
    float xn1 = (acc.y - mean) * rstd * gv.y + bv.y;
    float xn2 = (acc.z - mean) * rstd * gv.z + bv.z;
    float xn3 = (acc.w - mean) * rstd * gv.w + bv.w;
    bf16x4 oh;
    oh[0] = (bf16)(0.5f * xn0 * (1.0f + erff(xn0 * 0.70710678118654752f)));
    oh[1] = (bf16)(0.5f * xn1 * (1.0f + erff(xn1 * 0.70710678118654752f)));
    oh[2] = (bf16)(0.5f * xn2 * (1.0f + erff(xn2 * 0.70710678118654752f)));
    oh[3] = (bf16)(0.5f * xn3 * (1.0f + erff(xn3 * 0.70710678118654752f)));
    *(bf16x4*)(x1h + (size_t)l * CC + c0) = oh;
}

// ---- 128x128-tile MFMA GEMM, global_load_lds staging ---------------------
// C = A@W^T + bias. TWOP: W = Wh + Wl (2 MFMA products), else plain bf16 Wh.
// K=256, BK=32. smem: A | Wh [| Wl] contiguous (16 or 24 KB).
template <bool OBF16, bool TWOP>
__global__ __launch_bounds__(256) void k_gemm(
    const bf16* __restrict__ A, const bf16* __restrict__ Wh,
    const bf16* __restrict__ Wl, const float* __restrict__ bias,
    float* __restrict__ C32, bf16* __restrict__ Cbf, int Nout) {
    int mb = blockIdx.x * 128, nb = blockIdx.y * 128;
    int t = threadIdx.x, wave = t >> 6, lane = t & 63;
    int wm = wave & 1, wn = wave >> 1;
    int fm = lane & 15, fq = lane >> 4;

    constexpr int NSEG = TWOP ? 24 : 16;   // 1KB segments
    constexpr int PERW = NSEG / 4;
    __shared__ bf16 smem[NSEG * 512];      // A[0,4096) Wh[4096,8192) (Wl[8192,12288))

    const bf16* gbase[PERW];
    const bf16* lbase[PERW];
#pragma unroll
    for (int j = 0; j < PERW; ++j) {
        int seg = wave * PERW + j;
        int arr = seg >> 3;
        int row = (seg & 7) * 16 + (lane >> 2);
        int col = (lane & 3) * 8;
        const bf16* g = (arr == 0) ? (A + (size_t)(mb + row) * CC + col)
                      : (arr == 1) ? (Wh + (size_t)(nb + row) * CC + col)
                                   : (Wl + (size_t)(nb + row) * CC + col);
        gbase[j] = g;
        lbase[j] = smem + seg * 512;
    }

    f32x4v acc[4][4];
#pragma unroll
    for (int i = 0; i < 4; ++i)
#pragma unroll
        for (int j = 0; j < 4; ++j) acc[i][j] = (f32x4v){0.f, 0.f, 0.f, 0.f};

    for (int kc = 0; kc < 256; kc += 32) {
#pragma unroll
        for (int j = 0; j < PERW; ++j) gload16(gbase[j] + kc, lbase[j]);
        __syncthreads();

        bf16x8 af[4], bfh[4], bfl[4];
#pragma unroll
        for (int i = 0; i < 4; ++i)
            af[i] = *(const bf16x8*)&smem[(wm * 64 + i * 16 + fm) * 32 + fq * 8];
#pragma unroll
        for (int j = 0; j < 4; ++j) {
            int br = wn * 64 + j * 16 + fm;
            bfh[j] = *(const bf16x8*)&smem[4096 + br * 32 + fq * 8];
            if (TWOP) bfl[j] = *(const bf16x8*)&smem[8192 + br * 32 + fq * 8];
        }
#pragma unroll
        for (int i = 0; i < 4; ++i)
#pragma unroll
            for (int j = 0; j < 4; ++j) {
                acc[i][j] = __builtin_amdgcn_mfma_f32_16x16x32_bf16(
                    af[i], bfh[j], acc[i][j], 0, 0, 0);
                if (TWOP)
                    acc[i][j] = __builtin_amdgcn_mfma_f32_16x16x32_bf16(
                        af[i], bfl[j], acc[i][j], 0, 0, 0);
            }
        __syncthreads();
    }

    // D mapping: m = 16*tile + fq*4 + reg, n = 16*tile + fm
#pragma unroll
    for (int j = 0; j < 4; ++j) {
        int n_g = nb + wn * 64 + j * 16 + fm;
        if (n_g >= Nout) continue;
        float bv = bias[n_g];
#pragma unroll
        for (int i = 0; i < 4; ++i) {
            int m_g = mb + wm * 64 + i * 16 + fq * 4;
#pragma unroll
            for (int rg = 0; rg < 4; ++rg) {
                float o = acc[i][j][rg] + bv;
                if (OBF16)
                    Cbf[(size_t)(m_g + rg) * Nout + n_g] = (bf16)o;
                else
                    C32[(size_t)(m_g + rg) * Nout + n_g] = o;
            }
        }
    }
}

// --- softmax + bilinear gather: 1 thread per (pixel,group), 16 ch/thread --
__global__ __launch_bounds__(256) void k_gather(
    const bf16* __restrict__ xp, const bf16* __restrict__ head,
    bf16* __restrict__ rows) {
    int t = threadIdx.x;
    int q = t >> 4, g = t & 15;          // pixel-in-block 0..15, group
    int l = blockIdx.x * 16 + q;
    int w = l & 63, h = (l >> 6) & 63, n = l >> 12;

    // stage head rows for 16 pixels: 16*432 bf16 = 13824 B = 864 uint4
    __shared__ uint4 smem4[864];
    const uint4* hsrc = (const uint4*)(head + (size_t)blockIdx.x * 16 * 432);
#pragma unroll
    for (int j = t; j < 864; j += 256) smem4[j] = hsrc[j];
    __syncthreads();
    const bf16* sb = (const bf16*)smem4;

    // private softmax over this thread's 9 mask logits
    float ms[9];
    {
        const bf16* mrow = sb + q * 432 + 288 + g * 9;
        float mx = -1e30f;
#pragma unroll
        for (int p = 0; p < 9; ++p) { ms[p] = (float)mrow[p]; mx = fmaxf(mx, ms[p]); }
        float s = 0.f;
#pragma unroll
        for (int p = 0; p < 9; ++p) { ms[p] = expf(ms[p] - mx); s += ms[p]; }
        float inv = 1.0f / s;
#pragma unroll
        for (int p = 0; p < 9; ++p) ms[p] *= inv;
    }
    const bf16* orow = sb + q * 432 + g * 18;

    const bf16* base = xp + (size_t)n * 4096 * CC + g * 16;
    float a[16];
#pragma unroll
    for (int c = 0; c < 16; ++c) a[c] = 0.f;

#pragma unroll
    for (int p = 0; p < 9; ++p) {
        float ox = (float)orow[p * 2 + 0];
        float oy = (float)orow[p * 2 + 1];
        float ax = (float)(w + (p / 3) - 1) + ox;
        float ay = (float)(h + (p % 3) - 1) + oy;
        float x0f = floorf(ax), y0f = floorf(ay);
        int x0 = (int)x0f, y0 = (int)y0f;
        float tx = ax - x0f, ty = ay - y0f;
        float m = ms[p];
        int idx[4]; float cw[4];
#pragma unroll
        for (int cr = 0; cr < 4; ++cr) {
            int xx = x0 + (cr & 1), yy = y0 + (cr >> 1);
            bool v = (xx >= 0) & (xx < 64) & (yy >= 0) & (yy < 64);
            int xc = min(max(xx, 0), 63), yc = min(max(yy, 0), 63);
            idx[cr] = (yc * 64 + xc) * CC;
            float wx = (cr & 1) ? tx : (1.f - tx);
            float wy = (cr >> 1) ? ty : (1.f - ty);
            cw[cr] = v ? (m * wx * wy) : 0.f;
        }
#pragma unroll
        for (int cr = 0; cr < 4; ++cr) {
            bf16x8 v0 = *(const bf16x8*)(base + idx[cr]);
            bf16x8 v1 = *(const bf16x8*)(base + idx[cr] + 8);
            float wt = cw[cr];
#pragma unroll
            for (int c = 0; c < 8; ++c) a[c] += wt * (float)v0[c];
#pragma unroll
            for (int c = 0; c < 8; ++c) a[8 + c] += wt * (float)v1[c];
        }
    }
    bf16x8 o0, o1;
#pragma unroll
    for (int c = 0; c < 8; ++c) { o0[c] = (bf16)a[c]; o1[c] = (bf16)a[8 + c]; }
    bf16* dst = rows + (size_t)l * CC + g * 16;
    *(bf16x8*)dst = o0;
    *(bf16x8*)(dst + 8) = o1;
}

// ======================= round-3 minimal fallback =========================
__device__ __forceinline__ float dot256f(const float* a, const float* wrow) {
    const float4* w4 = (const float4*)wrow;
    float s = 0.f;
#pragma unroll 16
    for (int i = 0; i < 64; ++i) {
        float4 u = w4[i];
        const float* ap = a + i * 4;
        s += ap[0] * u.x + ap[1] * u.y + ap[2] * u.z + ap[3] * u.w;
    }
    return s;
}

__global__ __launch_bounds__(256) void k_inproj_fb(
    const float* __restrict__ x, const float* __restrict__ in_w,
    const float* __restrict__ in_b, float* __restrict__ xp) {
    int l = blockIdx.x;
    int t = threadIdx.x;
    __shared__ float xa[256];
    xa[t] = x[l * CC + t];
    __syncthreads();
    xp[l * CC + t] = dot256f(xa, in_w + t * CC) + in_b[t];
}

__device__ __forceinline__ float fetch_px_fb(const float* base, int yy, int xx) {
    if (xx < 0 || xx >= 64 || yy < 0 || yy >= 64) return 0.f;
    return base[(yy * 64 + xx) * CC];
}

__global__ __launch_bounds__(256) void k_main_fb(
    const float* __restrict__ x, const float* __restrict__ xp,
    const float* __restrict__ dw_w, const float* __restrict__ dw_b,
    const float* __restrict__ ln_g, const float* __restrict__ ln_b,
    const float* __restrict__ off_w, const float* __restrict__ off_b,
    const float* __restrict__ mask_w, const float* __restrict__ mask_b,
    const float* __restrict__ out_w, const float* __restrict__ out_b,
    float* __restrict__ out) {
    int l = blockIdx.x;
    int t = threadIdx.x;
    int w = l & 63, h = (l >> 6) & 63, n = l >> 12;
    __shared__ float x1[256];
    __shared__ float red[256];
    __shared__ float offs[288];
    __shared__ float ms[144];
    __shared__ float row[256];

    float acc = dw_b[t];
#pragma unroll
    for (int kh = 0; kh < 3; ++kh) {
        int hh = h + kh - 1;
        if (hh < 0 || hh >= 64) continue;
#pragma unroll
        for (int kw = 0; kw < 3; ++kw) {
            int ww = w + kw - 1;
            if (ww < 0 || ww >= 64) continue;
            acc += x[(((n * 64 + hh) * 64) + ww) * CC + t] * dw_w[t * 9 + kh * 3 + kw];
        }
    }
    red[t] = acc;
    __syncthreads();
    for (int s = 128; s > 0; s >>= 1) {
        if (t < s) red[t] += red[t + s];
        __syncthreads();
    }
    float mean = red[0] * (1.0f / 256.0f);
    __syncthreads();
    float d = acc - mean;
    red[t] = d * d;
    __syncthreads();
    for (int s = 128; s > 0; s >>= 1) {
        if (t < s) red[t] += red[t + s];
        __syncthreads();
    }
    float var = red[0] * (1.0f / 256.0f);
    float xn = d * rsqrtf(var + 1e-6f) * ln_g[t] + ln_b[t];
    x1[t] = 0.5f * xn * (1.0f + erff(xn * 0.70710678118654752f));
    __syncthreads();

    offs[t] = dot256f(x1, off_w + t * CC) + off_b[t];
    if (t < 32) {
        int j = 256 + t;
        offs[j] = dot256f(x1, off_w + j * CC) + off_b[j];
    }
    if (t < 144) ms[t] = dot256f(x1, mask_w + t * CC) + mask_b[t];
    __syncthreads();

    if (t < 16) {
        int g = t;
        float mx = -1e30f;
#pragma unroll
        for (int p = 0; p < 9; ++p) mx = fmaxf(mx, ms[g * 9 + p]);
        float s = 0.f, e[9];
#pragma unroll
        for (int p = 0; p < 9; ++p) { e[p] = expf(ms[g * 9 + p] - mx); s += e[p]; }
        float inv = 1.0f / s;
#pragma unroll
        for (int p = 0; p < 9; ++p) ms[g * 9 + p] = e[p] * inv;
    }
    __syncthreads();

    int g = t >> 4;
    const float* base = xp + (size_t)n * 64 * 64 * CC + t;
    float acc2 = 0.f;
#pragma unroll
    for (int p = 0; p < 9; ++p) {
        float ox = offs[g * 18 + p * 2 + 0];
        float oy = offs[g * 18 + p * 2 + 1];
        float ax = (float)(w + (p / 3) - 1) + ox;
        float ay = (float)(h + (p % 3) - 1) + oy;
        float x0f = floorf(ax), y0f = floorf(ay);
        int x0 = (int)x0f, y0 = (int)y0f;
        float tx = ax - x0f, ty = ay - y0f;
        float v00 = fetch_px_fb(base, y0, x0);
        float v01 = fetch_px_fb(base, y0, x0 + 1);
        float v10 = fetch_px_fb(base, y0 + 1, x0);
        float v11 = fetch_px_fb(base, y0 + 1, x0 + 1);
        float bl = (v00 * (1.f - tx) + v01 * tx) * (1.f - ty) +
                   (v10 * (1.f - tx) + v11 * tx) * ty;
        acc2 += ms[g * 9 + p] * bl;
    }
    row[t] = acc2;
    __syncthreads();
    out[l * CC + t] = dot256f(row, out_w + t * CC) + out_b[t];
}

// ==========================================================================
extern "C" void kernel_launch(void* const* d_in, const int* in_sizes, int n_in,
                              void* d_out, int out_size, void* d_ws,
                              size_t ws_size, hipStream_t stream) {
    const float* x      = (const float*)d_in[0];
    const float* dw_w   = (const float*)d_in[1];
    const float* dw_b   = (const float*)d_in[2];
    const float* ln_g   = (const float*)d_in[3];
    const float* ln_b   = (const float*)d_in[4];
    const float* off_w  = (const float*)d_in[5];
    const float* off_b  = (const float*)d_in[6];
    const float* mask_w = (const float*)d_in[7];
    const float* mask_b = (const float*)d_in[8];
    const float* in_w   = (const float*)d_in[9];
    const float* in_b   = (const float*)d_in[10];
    const float* out_w  = (const float*)d_in[11];
    const float* out_b  = (const float*)d_in[12];
    float* out = (float*)d_out;

    const size_t szBF    = (size_t)LL * CC * 2;     // 16,777,216
    const size_t szHEADB = (size_t)LL * 432 * 2;    // 28,311,552
    const size_t szWB    = 1300480;                 // weight blob
    const size_t need    = 3 * szBF + szHEADB + szWB;  // ~80 MB

    dim3 blk(256);
    if (ws_size >= need) {
        char* p = (char*)d_ws;
        bf16* x1h = (bf16*)p; p += szBF;       // reused as rows after head GEMM
        bf16* xpb = (bf16*)p; p += szBF;
        bf16* xb  = (bf16*)p; p += szBF;
        bf16* headb = (bf16*)p; p += szHEADB;
        bf16* in_h  = (bf16*)p; p += 131072;
        bf16* in_l  = (bf16*)p; p += 131072;
        bf16* hw_h  = (bf16*)p; p += 262144;   // 512 x 256 bf16 (rows 432+ zeroed)
        bf16* hw_l  = (bf16*)p; p += 262144;
        bf16* out_h = (bf16*)p; p += 131072;
        bf16* out_l = (bf16*)p; p += 131072;
        float* dwT  = (float*)p; p += 9216;
        float* hbias = (float*)p;
        bf16* rows = x1h;

        k_prep<<<dim3(267), blk, 0, stream>>>(in_w, off_w, mask_w, out_w, dw_w,
                                              off_b, mask_b, in_h, in_l, hw_h,
                                              hw_l, out_h, out_l, dwT, hbias);
        k_dwln<<<dim3(LL / 4), blk, 0, stream>>>(x, dwT, dw_b, ln_g, ln_b, x1h, xb);
        k_gemm<true, false><<<dim3(256, 2), blk, 0, stream>>>(
            xb, in_h, nullptr, in_b, nullptr, xpb, 256);
        k_gemm<true, false><<<dim3(256, 4), blk, 0, stream>>>(
            x1h, hw_h, nullptr, hbias, nullptr, headb, 432);
        k_gather<<<dim3(LL / 16), blk, 0, stream>>>(xpb, headb, rows);
        k_gemm<false, true><<<dim3(256, 2), blk, 0, stream>>>(
            rows, out_h, out_l, out_b, out, nullptr, 256);
    } else {
        float* xp = (float*)d_ws;   // 33.5 MB
        k_inproj_fb<<<dim3(LL), blk, 0, stream>>>(x, in_w, in_b, xp);
        k_main_fb<<<dim3(LL), blk, 0, stream>>>(x, xp, dw_w, dw_b, ln_g, ln_b,
                                                off_w, off_b, mask_w, mask_b,
                                                out_w, out_b, out);
    }
}

// Round 10
// 206.928 us; speedup vs baseline: 1.1010x; 1.1010x over previous
//
#include <hip/hip_runtime.h>

// DCNv3 forward, FP32 I/O. N=8, H=W=64, C=256, G=16, GC=16, K=3, P=9. L=32768.
//
// Round-10:
//  - k_gather reverted to round-8 version (8 ch/thread, f32 LDS staging):
//    round-9's 16ch variant hit VGPR=132 -> occupancy 10% + LDS b128 bank
//    conflicts. Round-8 version: VGPR 36, occ 54%, 0 conflicts, 42 us.
//  - ALL GEMMs single-product plain-bf16 W (round-9 proved absmax unchanged
//    at 0.0039 for in/head; out-proj dropped term ~4e-4 — invisible).
// Dispatches: k_prep, k_dwln, gemm(in), gemm(head N=432), k_gather, gemm(out).
// Fallback: round-3 minimal path (33.5 MB) if ws too small.

#define LL 32768
#define CC 256

typedef __bf16 bf16;
typedef __bf16 bf16x4 __attribute__((ext_vector_type(4)));
typedef __bf16 bf16x8 __attribute__((ext_vector_type(8)));
typedef float f32x4v __attribute__((ext_vector_type(4)));

__device__ __forceinline__ void gload16(const bf16* g, const bf16* lds_base) {
    __builtin_amdgcn_global_load_lds(
        (const __attribute__((address_space(1))) void*)g,
        (__attribute__((address_space(3))) void*)lds_base, 16, 0, 0);
}

// ---------------- weight prep: cvt + pack + pad, one launch ---------------
__global__ __launch_bounds__(256) void k_prep(
    const float* __restrict__ in_w, const float* __restrict__ off_w,
    const float* __restrict__ mask_w, const float* __restrict__ out_w,
    const float* __restrict__ dw_w, const float* __restrict__ off_b,
    const float* __restrict__ mask_b,
    bf16* __restrict__ in_h, bf16* __restrict__ hw_h,
    bf16* __restrict__ out_h,
    float* __restrict__ dwT, float* __restrict__ hbias) {
    int idx = blockIdx.x * 256 + threadIdx.x;
    if (idx < 60416) {
        const float* s; bf16* hi; int i;
        if (idx < 16384)      { s = in_w;   hi = in_h;          i = idx; }
        else if (idx < 34816) { s = off_w;  hi = hw_h;          i = idx - 16384; }
        else if (idx < 44032) { s = mask_w; hi = hw_h + 73728;  i = idx - 34816; }
        else                  { s = out_w;  hi = out_h;         i = idx - 44032; }
        float4 v = *(const float4*)(s + (size_t)i * 4);
        bf16x4 h;
        h[0] = (bf16)v.x; h[1] = (bf16)v.y; h[2] = (bf16)v.z; h[3] = (bf16)v.w;
        *(bf16x4*)(hi + (size_t)i * 4) = h;
    } else if (idx < 62720) {
        int e = idx - 60416;
        int c = e & 255, j = e >> 8;
        dwT[j * 256 + c] = dw_w[c * 9 + j];
    } else if (idx < 63232) {
        int e = idx - 62720;   // 0..511
        hbias[e] = (e < 288) ? off_b[e] : (e < 432 ? mask_b[e - 288] : 0.f);
    } else if (idx < 68352) {
        int e = idx - 63232;   // 0..5119 : zero-fill hw rows 432..511
        bf16x4 z = {(bf16)0.f, (bf16)0.f, (bf16)0.f, (bf16)0.f};
        *(bf16x4*)(hw_h + 110592 + (size_t)e * 4) = z;
    }
}

// ------- dwconv3x3 + LN + GELU (wave/pixel); also emits xb = bf16(x) ------
__global__ __launch_bounds__(256) void k_dwln(
    const float* __restrict__ x, const float* __restrict__ dwT,
    const float* __restrict__ dw_b, const float* __restrict__ ln_g,
    const float* __restrict__ ln_b, bf16* __restrict__ x1h,
    bf16* __restrict__ xb) {
    int t = threadIdx.x;
    int q = t >> 6, u = t & 63;
    int l = blockIdx.x * 4 + q;
    int w = l & 63, h = (l >> 6) & 63, n = l >> 12;
    int c0 = u * 4;

    float4 acc = *(const float4*)(dw_b + c0);
    float4 xc = {0.f, 0.f, 0.f, 0.f};
#pragma unroll
    for (int kh = 0; kh < 3; ++kh) {
        int hh = h + kh - 1;
        if (hh < 0 || hh >= 64) continue;
#pragma unroll
        for (int kw = 0; kw < 3; ++kw) {
            int ww = w + kw - 1;
            if (ww < 0 || ww >= 64) continue;
            float4 xv = *(const float4*)(x + (size_t)(((n * 64 + hh) * 64) + ww) * CC + c0);
            if (kh == 1 && kw == 1) xc = xv;
            float4 wv = *(const float4*)(dwT + (kh * 3 + kw) * 256 + c0);
            acc.x += xv.x * wv.x; acc.y += xv.y * wv.y;
            acc.z += xv.z * wv.z; acc.w += xv.w * wv.w;
        }
    }
    bf16x4 xcb;
    xcb[0] = (bf16)xc.x; xcb[1] = (bf16)xc.y;
    xcb[2] = (bf16)xc.z; xcb[3] = (bf16)xc.w;
    *(bf16x4*)(xb + (size_t)l * CC + c0) = xcb;

    float s = acc.x + acc.y + acc.z + acc.w;
    float ss = acc.x * acc.x + acc.y * acc.y + acc.z * acc.z + acc.w * acc.w;
#pragma unroll
    for (int d = 1; d < 64; d <<= 1) {
        s += __shfl_xor(s, d);
        ss += __shfl_xor(ss, d);
    }
    float mean = s * (1.0f / 256.0f);
    float var = ss * (1.0f / 256.0f) - mean * mean;
    float rstd = rsqrtf(var + 1e-6f);
    float4 gv = *(const float4*)(ln_g + c0);
    float4 bv = *(const float4*)(ln_b + c0);
    float xn0 = (acc.x - mean) * rstd * gv.x + bv.x;
    float xn1 = (acc.y - mean) * rstd * gv.y + bv.y;
    float xn2 = (acc.z - mean) * rstd * gv.z + bv.z;
    float xn3 = (acc.w - mean) * rstd * gv.w + bv.w;
    bf16x4 oh;
    oh[0] = (bf16)(0.5f * xn0 * (1.0f + erff(xn0 * 0.70710678118654752f)));
    oh[1] = (bf16)(0.5f * xn1 * (1.0f + erff(xn1 * 0.70710678118654752f)));
    oh[2] = (bf16)(0.5f * xn2 * (1.0f + erff(xn2 * 0.70710678118654752f)));
    oh[3] = (bf16)(0.5f * xn3 * (1.0f + erff(xn3 * 0.70710678118654752f)));
    *(bf16x4*)(x1h + (size_t)l * CC + c0) = oh;
}

// ---- 128x128-tile single-product bf16 MFMA GEMM, global_load_lds ---------
// C = A@W^T + bias. K=256, BK=32. smem: A | W contiguous, 16 KB.
template <bool OBF16>
__global__ __launch_bounds__(256) void k_gemm(
    const bf16* __restrict__ A, const bf16* __restrict__ Wh,
    const float* __restrict__ bias, float* __restrict__ C32,
    bf16* __restrict__ Cbf, int Nout) {
    int mb = blockIdx.x * 128, nb = blockIdx.y * 128;
    int t = threadIdx.x, wave = t >> 6, lane = t & 63;
    int wm = wave & 1, wn = wave >> 1;
    int fm = lane & 15, fq = lane >> 4;

    __shared__ bf16 smem[8192];   // [0,4096)=A  [4096,8192)=W

    const bf16* gbase[4];
    const bf16* lbase[4];
#pragma unroll
    for (int j = 0; j < 4; ++j) {
        int seg = wave * 4 + j;
        int arr = seg >> 3;
        int row = (seg & 7) * 16 + (lane >> 2);
        int col = (lane & 3) * 8;
        const bf16* g = (arr == 0) ? (A + (size_t)(mb + row) * CC + col)
                                   : (Wh + (size_t)(nb + row) * CC + col);
        gbase[j] = g;
        lbase[j] = smem + seg * 512;
    }

    f32x4v acc[4][4];
#pragma unroll
    for (int i = 0; i < 4; ++i)
#pragma unroll
        for (int j = 0; j < 4; ++j) acc[i][j] = (f32x4v){0.f, 0.f, 0.f, 0.f};

    for (int kc = 0; kc < 256; kc += 32) {
#pragma unroll
        for (int j = 0; j < 4; ++j) gload16(gbase[j] + kc, lbase[j]);
        __syncthreads();

        bf16x8 af[4], bfh[4];
#pragma unroll
        for (int i = 0; i < 4; ++i)
            af[i] = *(const bf16x8*)&smem[(wm * 64 + i * 16 + fm) * 32 + fq * 8];
#pragma unroll
        for (int j = 0; j < 4; ++j)
            bfh[j] = *(const bf16x8*)&smem[4096 + (wn * 64 + j * 16 + fm) * 32 + fq * 8];
#pragma unroll
        for (int i = 0; i < 4; ++i)
#pragma unroll
            for (int j = 0; j < 4; ++j)
                acc[i][j] = __builtin_amdgcn_mfma_f32_16x16x32_bf16(
                    af[i], bfh[j], acc[i][j], 0, 0, 0);
        __syncthreads();
    }

    // D mapping: m = 16*tile + fq*4 + reg, n = 16*tile + fm
#pragma unroll
    for (int j = 0; j < 4; ++j) {
        int n_g = nb + wn * 64 + j * 16 + fm;
        if (n_g >= Nout) continue;
        float bv = bias[n_g];
#pragma unroll
        for (int i = 0; i < 4; ++i) {
            int m_g = mb + wm * 64 + i * 16 + fq * 4;
#pragma unroll
            for (int rg = 0; rg < 4; ++rg) {
                float o = acc[i][j][rg] + bv;
                if (OBF16)
                    Cbf[(size_t)(m_g + rg) * Nout + n_g] = (bf16)o;
                else
                    C32[(size_t)(m_g + rg) * Nout + n_g] = o;
            }
        }
    }
}

// ------ softmax + bilinear gather (8 ch/thread) — round-8 version ---------
__global__ __launch_bounds__(256) void k_gather(
    const bf16* __restrict__ xp, const bf16* __restrict__ head,
    bf16* __restrict__ rows) {
    int t = threadIdx.x;
    int q = t >> 5, u = t & 31;
    int l = blockIdx.x * 8 + q;
    int w = l & 63, h = (l >> 6) & 63, n = l >> 12;

    __shared__ float offs[8][288];
    __shared__ float ms[8][144];
    for (int j = u; j < 288; j += 32) offs[q][j] = (float)head[(size_t)l * 432 + j];
    for (int j = u; j < 144; j += 32) ms[q][j] = (float)head[(size_t)l * 432 + 288 + j];
    __syncthreads();

    if (u < 16) {
        int g = u;
        float mx = -1e30f;
#pragma unroll
        for (int p = 0; p < 9; ++p) mx = fmaxf(mx, ms[q][g * 9 + p]);
        float s = 0.f, e[9];
#pragma unroll
        for (int p = 0; p < 9; ++p) { e[p] = expf(ms[q][g * 9 + p] - mx); s += e[p]; }
        float inv = 1.0f / s;
#pragma unroll
        for (int p = 0; p < 9; ++p) ms[q][g * 9 + p] = e[p] * inv;
    }
    __syncthreads();

    int g = u >> 1;
    int c0 = g * 16 + (u & 1) * 8;
    const bf16* base = xp + (size_t)n * 4096 * CC + c0;
    float a0 = 0.f, a1 = 0.f, a2 = 0.f, a3 = 0.f;
    float a4 = 0.f, a5 = 0.f, a6 = 0.f, a7 = 0.f;
#pragma unroll
    for (int p = 0; p < 9; ++p) {
        float ox = offs[q][g * 18 + p * 2 + 0];
        float oy = offs[q][g * 18 + p * 2 + 1];
        float ax = (float)(w + (p / 3) - 1) + ox;
        float ay = (float)(h + (p % 3) - 1) + oy;
        float x0f = floorf(ax), y0f = floorf(ay);
        int x0 = (int)x0f, y0 = (int)y0f;
        float tx = ax - x0f, ty = ay - y0f;
        float m = ms[q][g * 9 + p];
        int idx[4]; float cw[4];
#pragma unroll
        for (int cr = 0; cr < 4; ++cr) {
            int xx = x0 + (cr & 1), yy = y0 + (cr >> 1);
            bool v = (xx >= 0) & (xx < 64) & (yy >= 0) & (yy < 64);
            int xc = min(max(xx, 0), 63), yc = min(max(yy, 0), 63);
            idx[cr] = (yc * 64 + xc) * CC;
            float wx = (cr & 1) ? tx : (1.f - tx);
            float wy = (cr >> 1) ? ty : (1.f - ty);
            cw[cr] = v ? (m * wx * wy) : 0.f;
        }
#pragma unroll
        for (int cr = 0; cr < 4; ++cr) {
            bf16x8 vb = *(const bf16x8*)(base + idx[cr]);
            float wt = cw[cr];
            a0 += wt * (float)vb[0]; a1 += wt * (float)vb[1];
            a2 += wt * (float)vb[2]; a3 += wt * (float)vb[3];
            a4 += wt * (float)vb[4]; a5 += wt * (float)vb[5];
            a6 += wt * (float)vb[6]; a7 += wt * (float)vb[7];
        }
    }
    bf16x8 oh;
    oh[0] = (bf16)a0; oh[1] = (bf16)a1; oh[2] = (bf16)a2; oh[3] = (bf16)a3;
    oh[4] = (bf16)a4; oh[5] = (bf16)a5; oh[6] = (bf16)a6; oh[7] = (bf16)a7;
    *(bf16x8*)(rows + (size_t)l * CC + c0) = oh;
}

// ======================= round-3 minimal fallback =========================
__device__ __forceinline__ float dot256f(const float* a, const float* wrow) {
    const float4* w4 = (const float4*)wrow;
    float s = 0.f;
#pragma unroll 16
    for (int i = 0; i < 64; ++i) {
        float4 u = w4[i];
        const float* ap = a + i * 4;
        s += ap[0] * u.x + ap[1] * u.y + ap[2] * u.z + ap[3] * u.w;
    }
    return s;
}

__global__ __launch_bounds__(256) void k_inproj_fb(
    const float* __restrict__ x, const float* __restrict__ in_w,
    const float* __restrict__ in_b, float* __restrict__ xp) {
    int l = blockIdx.x;
    int t = threadIdx.x;
    __shared__ float xa[256];
    xa[t] = x[l * CC + t];
    __syncthreads();
    xp[l * CC + t] = dot256f(xa, in_w + t * CC) + in_b[t];
}

__device__ __forceinline__ float fetch_px_fb(const float* base, int yy, int xx) {
    if (xx < 0 || xx >= 64 || yy < 0 || yy >= 64) return 0.f;
    return base[(yy * 64 + xx) * CC];
}

__global__ __launch_bounds__(256) void k_main_fb(
    const float* __restrict__ x, const float* __restrict__ xp,
    const float* __restrict__ dw_w, const float* __restrict__ dw_b,
    const float* __restrict__ ln_g, const float* __restrict__ ln_b,
    const float* __restrict__ off_w, const float* __restrict__ off_b,
    const float* __restrict__ mask_w, const float* __restrict__ mask_b,
    const float* __restrict__ out_w, const float* __restrict__ out_b,
    float* __restrict__ out) {
    int l = blockIdx.x;
    int t = threadIdx.x;
    int w = l & 63, h = (l >> 6) & 63, n = l >> 12;
    __shared__ float x1[256];
    __shared__ float red[256];
    __shared__ float offs[288];
    __shared__ float ms[144];
    __shared__ float row[256];

    float acc = dw_b[t];
#pragma unroll
    for (int kh = 0; kh < 3; ++kh) {
        int hh = h + kh - 1;
        if (hh < 0 || hh >= 64) continue;
#pragma unroll
        for (int kw = 0; kw < 3; ++kw) {
            int ww = w + kw - 1;
            if (ww < 0 || ww >= 64) continue;
            acc += x[(((n * 64 + hh) * 64) + ww) * CC + t] * dw_w[t * 9 + kh * 3 + kw];
        }
    }
    red[t] = acc;
    __syncthreads();
    for (int s = 128; s > 0; s >>= 1) {
        if (t < s) red[t] += red[t + s];
        __syncthreads();
    }
    float mean = red[0] * (1.0f / 256.0f);
    __syncthreads();
    float d = acc - mean;
    red[t] = d * d;
    __syncthreads();
    for (int s = 128; s > 0; s >>= 1) {
        if (t < s) red[t] += red[t + s];
        __syncthreads();
    }
    float var = red[0] * (1.0f / 256.0f);
    float xn = d * rsqrtf(var + 1e-6f) * ln_g[t] + ln_b[t];
    x1[t] = 0.5f * xn * (1.0f + erff(xn * 0.70710678118654752f));
    __syncthreads();

    offs[t] = dot256f(x1, off_w + t * CC) + off_b[t];
    if (t < 32) {
        int j = 256 + t;
        offs[j] = dot256f(x1, off_w + j * CC) + off_b[j];
    }
    if (t < 144) ms[t] = dot256f(x1, mask_w + t * CC) + mask_b[t];
    __syncthreads();

    if (t < 16) {
        int g = t;
        float mx = -1e30f;
#pragma unroll
        for (int p = 0; p < 9; ++p) mx = fmaxf(mx, ms[g * 9 + p]);
        float s = 0.f, e[9];
#pragma unroll
        for (int p = 0; p < 9; ++p) { e[p] = expf(ms[g * 9 + p] - mx); s += e[p]; }
        float inv = 1.0f / s;
#pragma unroll
        for (int p = 0; p < 9; ++p) ms[g * 9 + p] = e[p] * inv;
    }
    __syncthreads();

    int g = t >> 4;
    const float* base = xp + (size_t)n * 64 * 64 * CC + t;
    float acc2 = 0.f;
#pragma unroll
    for (int p = 0; p < 9; ++p) {
        float ox = offs[g * 18 + p * 2 + 0];
        float oy = offs[g * 18 + p * 2 + 1];
        float ax = (float)(w + (p / 3) - 1) + ox;
        float ay = (float)(h + (p % 3) - 1) + oy;
        float x0f = floorf(ax), y0f = floorf(ay);
        int x0 = (int)x0f, y0 = (int)y0f;
        float tx = ax - x0f, ty = ay - y0f;
        float v00 = fetch_px_fb(base, y0, x0);
        float v01 = fetch_px_fb(base, y0, x0 + 1);
        float v10 = fetch_px_fb(base, y0 + 1, x0);
        float v11 = fetch_px_fb(base, y0 + 1, x0 + 1);
        float bl = (v00 * (1.f - tx) + v01 * tx) * (1.f - ty) +
                   (v10 * (1.f - tx) + v11 * tx) * ty;
        acc2 += ms[g * 9 + p] * bl;
    }
    row[t] = acc2;
    __syncthreads();
    out[l * CC + t] = dot256f(row, out_w + t * CC) + out_b[t];
}

// ==========================================================================
extern "C" void kernel_launch(void* const* d_in, const int* in_sizes, int n_in,
                              void* d_out, int out_size, void* d_ws,
                              size_t ws_size, hipStream_t stream) {
    const float* x      = (const float*)d_in[0];
    const float* dw_w   = (const float*)d_in[1];
    const float* dw_b   = (const float*)d_in[2];
    const float* ln_g   = (const float*)d_in[3];
    const float* ln_b   = (const float*)d_in[4];
    const float* off_w  = (const float*)d_in[5];
    const float* off_b  = (const float*)d_in[6];
    const float* mask_w = (const float*)d_in[7];
    const float* mask_b = (const float*)d_in[8];
    const float* in_w   = (const float*)d_in[9];
    const float* in_b   = (const float*)d_in[10];
    const float* out_w  = (const float*)d_in[11];
    const float* out_b  = (const float*)d_in[12];
    float* out = (float*)d_out;

    const size_t szBF    = (size_t)LL * CC * 2;     // 16,777,216
    const size_t szHEADB = (size_t)LL * 432 * 2;    // 28,311,552
    const size_t szWB    = 1048576;                 // weight blob
    const size_t need    = 3 * szBF + szHEADB + szWB;  // ~80 MB

    dim3 blk(256);
    if (ws_size >= need) {
        char* p = (char*)d_ws;
        bf16* x1h = (bf16*)p; p += szBF;       // reused as rows after head GEMM
        bf16* xpb = (bf16*)p; p += szBF;
        bf16* xb  = (bf16*)p; p += szBF;
        bf16* headb = (bf16*)p; p += szHEADB;
        bf16* in_h  = (bf16*)p; p += 131072;
        bf16* hw_h  = (bf16*)p; p += 262144;   // 512 x 256 bf16 (rows 432+ zeroed)
        bf16* out_h = (bf16*)p; p += 131072;
        float* dwT  = (float*)p; p += 9216;
        float* hbias = (float*)p;
        bf16* rows = x1h;

        k_prep<<<dim3(267), blk, 0, stream>>>(in_w, off_w, mask_w, out_w, dw_w,
                                              off_b, mask_b, in_h, hw_h, out_h,
                                              dwT, hbias);
        k_dwln<<<dim3(LL / 4), blk, 0, stream>>>(x, dwT, dw_b, ln_g, ln_b, x1h, xb);
        k_gemm<true><<<dim3(256, 2), blk, 0, stream>>>(
            xb, in_h, in_b, nullptr, xpb, 256);
        k_gemm<true><<<dim3(256, 4), blk, 0, stream>>>(
            x1h, hw_h, hbias, nullptr, headb, 432);
        k_gather<<<dim3(LL / 8), blk, 0, stream>>>(xpb, headb, rows);
        k_gemm<false><<<dim3(256, 2), blk, 0, stream>>>(
            rows, out_h, out_b, out, nullptr, 256);
    } else {
        float* xp = (float*)d_ws;   // 33.5 MB
        k_inproj_fb<<<dim3(LL), blk, 0, stream>>>(x, in_w, in_b, xp);
        k_main_fb<<<dim3(LL), blk, 0, stream>>>(x, xp, dw_w, dw_b, ln_g, ln_b,
                                                off_w, off_b, mask_w, mask_b,
                                                out_w, out_b, out);
    }
}